// Round 15
// baseline (46.741 us; speedup 1.0000x reference)
//
#include <hip/hip_runtime.h>
#include <math.h>

#define NN   8
#define INCH 32
#define INN  50000
#define OUTC 64
#define OUTN 8192
#define DD   32
#define CC   256            // NN*INCH
#define NPL  8              // c-planes (== #XCDs)
#define PLDW ((size_t)INN * 16)   // dwords per plane: 50000 rows x 16 dwords(64B) = 3.2 MB
#define JW   512            // prep j-window; 50000 = 97*512 + 336 (tail: 336 = 21*256/16 clean)

typedef unsigned short ushortT;

__device__ __forceinline__ unsigned f2bf_u(float f) {
  unsigned u = __float_as_uint(f);
  return (u + 0x7FFFu + ((u >> 16) & 1u)) >> 16;   // round-nearest-even
}

// dword convention: yTc plane p, row j, pos q (0..15) holds bf16 pair (c_lo, c_lo+128),
// c_lo = p*16 + q.

// Kernel 1: slab prep. Block (p=b%8 -> XCD p, j-chunk 512). Owns the 32 c-rows of
// plane p; per row a SEQUENTIAL 2KB read stream; writes one 32KB contiguous run of
// plane p (dirty lines stay in XCD-p L2 for the gather).
__global__ __launch_bounds__(256) void prep_kernel(
    const float* __restrict__ x, const float* __restrict__ nf, unsigned* __restrict__ yTc) {
  __shared__ ushortT tile[JW][34];   // j-major, 34.8 KB; slot = 2*(rl&15) + hi
  const int t = threadIdx.x;
  const int p  = blockIdx.x & 7;           // plane == XCD
  const int b2 = blockIdx.x >> 3;          // 0..97
  const int j0 = b2 * JW;
  const int jmax = min(JW, INN - j0);      // 336 for b2=97

  const int rl = t >> 3;                   // row_local 0..31
  const int m  = t & 7;                    // 16B segment within 128B step
  const int cg = p * 16 + (rl & 15) + ((rl >> 4) << 7);   // global c row
  const int slot = ((rl & 15) << 1) | (rl >> 4);
  const float* xr = x + (size_t)cg * INN + j0;
  const float* nr = nf + (size_t)(((p & 1) << 4) + (rl & 15)) * INN + j0;

  // load: per instr 8 rows x 128B; per row over i: sequential 2KB stream
  #pragma unroll 8
  for (int i = 0; i < 16; ++i) {
    const int jj = i * 32 + m * 4;
    if (jj < jmax) {
      const float4 xv = *(const float4*)(xr + jj);
      const float4 nv = *(const float4*)(nr + jj);
      // u16 LDS writes, banks (4m+17e+c')%32 -> <=2-way (free)
      tile[jj + 0][slot] = (ushortT)f2bf_u(xv.x * nv.x);
      tile[jj + 1][slot] = (ushortT)f2bf_u(xv.y * nv.y);
      tile[jj + 2][slot] = (ushortT)f2bf_u(xv.z * nv.z);
      tile[jj + 3][slot] = (ushortT)f2bf_u(xv.w * nv.w);
    }
  }
  __syncthreads();

  // store: dword dw = iter*256 + t -> (jl = dw>>4, q = dw&15); LDS pair-slot read is one
  // aligned dword = lo | hi<<16; global: 1KB contiguous per block-step. jmax*16 % 256 == 0.
  unsigned* dst = yTc + (size_t)p * PLDW + (size_t)j0 * 16;
  const int ndw = jmax * 16;
  for (int dw = t; dw < ndw; dw += 256) {
    const int jl = dw >> 4;
    const int q  = dw & 15;
    dst[dw] = *(const unsigned*)&tile[jl][2 * q];
  }
}

// Kernel 2 (R11, proven): c-sliced gather. 2048 blocks (plane=b%8 -> XCD-pinned, 32 o's),
// 8 blocks/CU. Thread (osub,cq,dh): 16 d-iters, uint4 loads, shfl_xor(1) merge.
__global__ __launch_bounds__(256, 8) void gather_kernel(
    const unsigned* __restrict__ yTc, const int* __restrict__ A, unsigned* __restrict__ red32) {
  __shared__ int Al[32 * 33];   // A[o0..o0+31][0..31], padded
  const int t = threadIdx.x;
  const int ck = blockIdx.x & 7;
  const int ob = blockIdx.x >> 3;   // 0..255
  const int o0 = ob * 32;

  #pragma unroll
  for (int k = 0; k < 4; ++k) {
    const int f = k * 256 + t;                      // 0..1023, coalesced
    Al[(f >> 5) * 33 + (f & 31)] = A[(size_t)o0 * DD + f];
  }
  __syncthreads();

  const unsigned* plane = yTc + (size_t)ck * PLDW;
  const int osub = t >> 3;          // 0..31
  const int cq   = (t >> 1) & 3;    // 0..3
  const int dh   = t & 1;           // 0..1

  float l0 = -INFINITY, l1 = -INFINITY, l2 = -INFINITY, l3 = -INFINITY;
  float h0 = -INFINITY, h1 = -INFINITY, h2 = -INFINITY, h3 = -INFINITY;

  #pragma unroll 8
  for (int k = 0; k < 16; ++k) {
    const int d = 2 * k + dh;
    const int idx = Al[osub * 33 + d];   // conflict-free broadcast
    const uint4 v = *(const uint4*)(plane + (size_t)idx * 16 + cq * 4);  // 16x64B segs/instr
    l0 = fmaxf(l0, __uint_as_float(v.x << 16));  h0 = fmaxf(h0, __uint_as_float(v.x & 0xffff0000u));
    l1 = fmaxf(l1, __uint_as_float(v.y << 16));  h1 = fmaxf(h1, __uint_as_float(v.y & 0xffff0000u));
    l2 = fmaxf(l2, __uint_as_float(v.z << 16));  h2 = fmaxf(h2, __uint_as_float(v.z & 0xffff0000u));
    l3 = fmaxf(l3, __uint_as_float(v.w << 16));  h3 = fmaxf(h3, __uint_as_float(v.w & 0xffff0000u));
  }
  // merge lane pairs (t, t^1)
  l0 = fmaxf(l0, __shfl_xor(l0, 1));  h0 = fmaxf(h0, __shfl_xor(h0, 1));
  l1 = fmaxf(l1, __shfl_xor(l1, 1));  h1 = fmaxf(h1, __shfl_xor(h1, 1));
  l2 = fmaxf(l2, __shfl_xor(l2, 1));  h2 = fmaxf(h2, __shfl_xor(h2, 1));
  l3 = fmaxf(l3, __shfl_xor(l3, 1));  h3 = fmaxf(h3, __shfl_xor(h3, 1));

  uint2 pk;
  if (dh == 0) {
    pk.x = (__float_as_uint(l0) >> 16) | (__float_as_uint(h0) & 0xffff0000u);
    pk.y = (__float_as_uint(l1) >> 16) | (__float_as_uint(h1) & 0xffff0000u);
  } else {
    pk.x = (__float_as_uint(l2) >> 16) | (__float_as_uint(h2) & 0xffff0000u);
    pk.y = (__float_as_uint(l3) >> 16) | (__float_as_uint(h3) & 0xffff0000u);
  }
  *(uint2*)(red32 + (size_t)(o0 + osub) * 128 + ck * 16 + cq * 4 + dh * 2) = pk;
}

// Kernel 3 (proven): out[n,k,o] = sum_i red[o][n*32+i]*ft[i][k] + bias[k][o]
__global__ __launch_bounds__(256) void out_kernel(
    const unsigned* __restrict__ red32, const float* __restrict__ ft,
    const float* __restrict__ bias, float* __restrict__ out) {
  __shared__ float rtile[64][65];   // pad 65 -> <=2-way
  __shared__ float ftl[32][64];
  const int t = threadIdx.x;
  const int lane = t & 63;
  const int wave = t >> 6;
  const int np = blockIdx.x >> 7;   // 0..3
  const int ot = blockIdx.x & 127;  // 0..127
  const int o0 = ot * 64;
  const int hi = np >> 1;
  const int sb = (np & 1) * 64;

  #pragma unroll
  for (int q = 0; q < 8; ++q) {
    const int idx = q * 256 + t;
    ftl[idx >> 6][idx & 63] = ft[idx];
  }
  #pragma unroll
  for (int i = 0; i < 2; ++i) {
    const int r = (t >> 3) + 32 * i;
    const int g = t & 7;
    const unsigned* src = red32 + (size_t)(o0 + r) * 128 + sb + g * 8;
    const uint4 v0 = *(const uint4*)(src);
    const uint4 v1 = *(const uint4*)(src + 4);
    const unsigned w[8] = {v0.x, v0.y, v0.z, v0.w, v1.x, v1.y, v1.z, v1.w};
    float* dst = &rtile[r][g * 8];
    #pragma unroll
    for (int u = 0; u < 8; ++u)
      dst[u] = __uint_as_float(hi ? (w[u] & 0xffff0000u) : (w[u] << 16));
  }
  __syncthreads();

  const int n  = np * 2 + (wave & 1);
  const int kh = (wave >> 1) * 32;
  const int cb = (wave & 1) * 32;

  float rv[32];
  #pragma unroll
  for (int i = 0; i < 32; ++i) rv[i] = rtile[lane][cb + i];   // 2-way

  float acc[32];
  #pragma unroll
  for (int kk = 0; kk < 32; ++kk) acc[kk] = 0.f;
  #pragma unroll
  for (int i = 0; i < 32; ++i) {
    #pragma unroll
    for (int kk = 0; kk < 32; ++kk)
      acc[kk] += rv[i] * ftl[i][kh + kk];   // uniform addr -> broadcast
  }

  float* op = out + (size_t)n * OUTC * OUTN + o0 + lane;
  const float* bp = bias + o0 + lane;
  #pragma unroll
  for (int kk = 0; kk < 32; ++kk) {
    const int k = kh + kk;
    op[(size_t)k * OUTN] = acc[kk] + bp[(size_t)k * OUTN];   // 256B-contiguous stores
  }
}

extern "C" void kernel_launch(void* const* d_in, const int* in_sizes, int n_in,
                              void* d_out, int out_size, void* d_ws, size_t ws_size,
                              hipStream_t stream) {
  const float* x    = (const float*)d_in[0];
  const float* nf   = (const float*)d_in[1];
  const float* ft   = (const float*)d_in[2];
  const float* bias = (const float*)d_in[3];
  const int*   A    = (const int*)d_in[4];
  float* out = (float*)d_out;

  unsigned* yTc   = (unsigned*)d_ws;                           // 8 x 3.2 MB = 25.6 MB
  unsigned* red32 = (unsigned*)((char*)d_ws + NPL * PLDW * 4); // 8192*128*4 = 4.2 MB

  hipLaunchKernelGGL(prep_kernel,   dim3(((INN + JW - 1) / JW) * NPL), dim3(256), 0, stream, x, nf, yTc);
  hipLaunchKernelGGL(gather_kernel, dim3((OUTN / 32) * NPL),           dim3(256), 0, stream, yTc, A, red32);
  hipLaunchKernelGGL(out_kernel,    dim3(512),                         dim3(256), 0, stream, red32, ft, bias, out);
}